// Round 15
// baseline (188.491 us; speedup 1.0000x reference)
//
#include <hip/hip_runtime.h>

#define NN 100000
#define NE 800000
#define NI 1600000      // items = 2E (both directions)
#define NB 391          // coarse buckets = ceil(2N / 512)
#define IPB 6250        // items per block in hist/scatter (256 blocks)

// grid split for fused prep kernel
#define GB_CVT 12500    // cvt_x blocks (NN*32 float4 / 256)
#define GB_PW  128      // prep_w blocks
#define GB_HIST 256     // hist blocks

// ---- workspace layout (bytes) ----
#define OFF_INV    0u           // float[2N]   [0,N)=row-keyed inv, [N,2N)=col-keyed inv
#define OFF_OFFS   800000u      // int[2N+1]
#define OFF_HIST   1601600u     // int[NB*256]
#define OFF_CSRC   2001984u     // int[2E]
#define OFF_XB     8401984u     // bf16[N*128]
#define OFF_PAIRS  34001984u    // uint[2E] packed (val<<9 | key&511)
#define OFF_WT     85201984u    // bf16[128*256] WT[c][k]: k<128 -> W_ds, else W_sd
#define OFF_BIAS   85267520u    // float[128] 0.5*(b_ds+b_sd)
#define OFF_TOT    85268032u    // int[NB]

typedef short short8 __attribute__((ext_vector_type(8)));
typedef unsigned short u16x8 __attribute__((ext_vector_type(8)));
typedef float f32x4 __attribute__((ext_vector_type(4)));
typedef float f32x8 __attribute__((ext_vector_type(8)));

__device__ __forceinline__ unsigned short f2bf(float f) {
    unsigned u = __float_as_uint(f);
    u = (u + 0x7FFFu + ((u >> 16) & 1u)) >> 16;   // RNE
    return (unsigned short)u;
}
__device__ __forceinline__ float b2f(unsigned short h) {
    return __uint_as_float(((unsigned)h) << 16);
}
__device__ __forceinline__ f32x8 bvec2f(u16x8 v) {
    f32x8 r;
#pragma unroll
    for (int i = 0; i < 8; ++i) r[i] = b2f(v[i]);
    return r;
}

// item i: i<NE  -> key=row=ei[i],      val=col=ei[NE+i]  (in-agg, keyed by row)
//         i>=NE -> key=NN+col=NN+ei[i], val=row=ei[i-NE] (out-agg, keyed by col)

// Fused: cvt_x | prep_w | hist — mutually independent work
__global__ __launch_bounds__(256) void k_prep(
    const float4* __restrict__ x4, ushort4* __restrict__ xb4,
    const float* __restrict__ Wds, const float* __restrict__ Wsd,
    const float* __restrict__ bds, const float* __restrict__ bsd,
    unsigned short* __restrict__ wt, float* __restrict__ bias,
    const int* __restrict__ ei, int* __restrict__ hist) {
    __shared__ int h[NB];
    int bid = blockIdx.x;
    if (bid < GB_CVT) {
        int i = bid * 256 + threadIdx.x;           // < NN*32 exactly
        float4 v = x4[i];
        ushort4 o;
        o.x = f2bf(v.x); o.y = f2bf(v.y); o.z = f2bf(v.z); o.w = f2bf(v.w);
        xb4[i] = o;
        return;
    }
    if (bid < GB_CVT + GB_PW) {
        int id = (bid - GB_CVT) * 256 + threadIdx.x;   // < 32768 exactly
        int c = id & 127;
        int k = id >> 7;
        float v = (k < 128) ? Wds[k * 128 + c] : Wsd[(k - 128) * 128 + c];
        wt[c * 256 + k] = f2bf(v);
        if (k == 0) bias[c] = 0.5f * (bds[c] + bsd[c]);
        return;
    }
    int hb = bid - GB_CVT - GB_PW;                  // hist block 0..255
    for (int k = threadIdx.x; k < NB; k += 256) h[k] = 0;
    __syncthreads();
    int base = hb * IPB;
    for (int t = threadIdx.x; t < IPB; t += 256) {
        int i = base + t;
        int key = (i < NE) ? ei[i] : (NN + ei[i]);
        atomicAdd(&h[key >> 9], 1);
    }
    __syncthreads();
    for (int k = threadIdx.x; k < NB; k += 256) hist[k * 256 + hb] = h[k];
}

// Per-bucket column scan: hist[k][b] -> local exclusive scan, tot[k] = total
__global__ __launch_bounds__(256) void k_colscan(int* __restrict__ hist,
                                                 int* __restrict__ tot) {
    __shared__ int sA[256], sB[256];
    int k = blockIdx.x, tid = threadIdx.x;
    int v = hist[k * 256 + tid];
    sA[tid] = v;
    __syncthreads();
    int *src = sA, *dst = sB;
    for (int st = 1; st < 256; st <<= 1) {
        dst[tid] = src[tid] + ((tid >= st) ? src[tid - st] : 0);
        __syncthreads();
        int* tp = src; src = dst; dst = tp;
    }
    hist[k * 256 + tid] = src[tid] - v;   // local exclusive scan
    if (tid == 255) tot[k] = src[255];
}

// scatter packed items; per-block cursor = in-LDS scan of tot + local hist base
__global__ __launch_bounds__(256) void k_scatter(const int* __restrict__ ei,
                                                 const int* __restrict__ hist,
                                                 const int* __restrict__ tot,
                                                 unsigned int* __restrict__ pairs) {
    __shared__ int sA[512], sB[512];
    __shared__ int cur[NB];
    const int tid = threadIdx.x;
    for (int k = tid; k < 512; k += 256) sA[k] = (k < NB) ? tot[k] : 0;
    __syncthreads();
    int *src = sA, *dst = sB;
    for (int st = 1; st < 512; st <<= 1) {
        for (int k = tid; k < 512; k += 256) dst[k] = src[k] + ((k >= st) ? src[k - st] : 0);
        __syncthreads();
        int* tp = src; src = dst; dst = tp;
    }
    for (int k = tid; k < NB; k += 256)
        cur[k] = ((k > 0) ? src[k - 1] : 0) + hist[k * 256 + blockIdx.x];
    __syncthreads();
    int base = blockIdx.x * IPB;
    for (int t = tid; t < IPB; t += 256) {
        int i = base + t;
        int e = ei[i];
        int key, val;
        if (i < NE) { key = e;      val = ei[NE + i]; }
        else        { key = NN + e; val = ei[i - NE]; }
        int pos = atomicAdd(&cur[key >> 9], 1);
        pairs[pos] = ((unsigned)val << 9) | (unsigned)(key & 511);
    }
}

// one block per bucket: bucket base from in-LDS tot scan, then count/scan/emit
__global__ __launch_bounds__(256) void k_bucket(const unsigned int* __restrict__ pairs,
                                                const int* __restrict__ tot,
                                                int* __restrict__ csr_src,
                                                int* __restrict__ offsets,
                                                float* __restrict__ inv) {
    __shared__ int sA[512], sB[512], cur[512];
    const int h = blockIdx.x, tid = threadIdx.x;
    // phase 0: scan tot -> bucket bounds
    for (int k = tid; k < 512; k += 256) sA[k] = (k < NB) ? tot[k] : 0;
    __syncthreads();
    int *src = sA, *dst = sB;
    for (int st = 1; st < 512; st <<= 1) {
        for (int k = tid; k < 512; k += 256) dst[k] = src[k] + ((k >= st) ? src[k - st] : 0);
        __syncthreads();
        int* tp = src; src = dst; dst = tp;
    }
    const int s0 = (h > 0) ? src[h - 1] : 0;
    const int s1 = src[h];
    __syncthreads();
    // phase 1: local key count
    for (int k = tid; k < 512; k += 256) sA[k] = 0;
    __syncthreads();
    for (int i = s0 + tid; i < s1; i += 256) {
        atomicAdd(&sA[pairs[i] & 511], 1);
    }
    __syncthreads();
    src = sA; dst = sB;
    for (int st = 1; st < 512; st <<= 1) {
        for (int k = tid; k < 512; k += 256) dst[k] = src[k] + ((k >= st) ? src[k - st] : 0);
        __syncthreads();
        int* tp = src; src = dst; dst = tp;
    }
    for (int k = tid; k < 512; k += 256) {
        int incl = src[k];
        int excl = (k > 0) ? src[k - 1] : 0;
        cur[k] = s0 + excl;
        int gkey = h * 512 + k;
        if (gkey <= 2 * NN) offsets[gkey] = s0 + excl;
        if (gkey < 2 * NN) {
            int cnt = incl - excl;
            inv[gkey] = (cnt > 0) ? rsqrtf((float)cnt) : 0.0f;
        }
    }
    __syncthreads();
    for (int i = s0 + tid; i < s1; i += 256) {
        unsigned int p = pairs[i];
        int pos = atomicAdd(&cur[p & 511], 1);
        csr_src[pos] = (int)(p >> 9);
    }
}

// Fused gather + GEMM — R11 geometry + pre-barrier B-fragment prefetch.
// Block = 512 threads (8 waves), 16 nodes, 32 segments, grid 6250.
// The 8 wt B-fragments (128B/lane) are loaded at kernel ENTRY: their L2
// fetch latency overlaps the ~90us gather phase instead of sitting serial
// after the barrier. Post-barrier = pure LDS reads + MFMA + stores.
__global__ __launch_bounds__(512) void k_gather_gemm(
    const u16x8* __restrict__ xb8, const int* __restrict__ offsets,
    const int* __restrict__ csr_src, const float* __restrict__ inv,
    const unsigned short* __restrict__ wt, const float* __restrict__ bias,
    float* __restrict__ out) {
    __shared__ unsigned short a_lds[16][264];

    const int wave = threadIdx.x >> 6;
    const int lane = threadIdx.x & 63;
    const int grp = lane >> 4;                 // 0..3
    const int cl = lane & 15;
    const int nl = wave * 2 + (grp >> 1);      // local node 0..15
    const int n = blockIdx.x * 16 + nl;        // 6250*16 == NN exactly
    const int dir = grp & 1;                   // 0 = in-agg, 1 = out-agg

    // ---- prefetch GEMM B-operands + bias (independent of gather) ----
    const int fr = lane & 15;
    const int kg = (lane >> 4) * 8;
    const int col = wave * 16 + fr;
    short8 bfrag[8];
#pragma unroll
    for (int s = 0; s < 8; ++s)
        bfrag[s] = *(const short8*)(wt + col * 256 + s * 32 + kg);
    const float b = bias[col];

    // ---- gather phase ----
    {
        int key = dir * NN + n;
        int s0 = offsets[key], s1 = offsets[key + 1];
        const float* __restrict__ srcinv = inv + (dir ^ 1) * NN;

        f32x8 acc = {0.f, 0.f, 0.f, 0.f, 0.f, 0.f, 0.f, 0.f};
        int e = s0;
        for (; e + 4 <= s1; e += 4) {
            int i0 = csr_src[e];
            int i1 = csr_src[e + 1];
            int i2 = csr_src[e + 2];
            int i3 = csr_src[e + 3];
            float w0 = srcinv[i0], w1 = srcinv[i1], w2 = srcinv[i2], w3 = srcinv[i3];
            u16x8 v0 = xb8[i0 * 16 + cl];
            u16x8 v1 = xb8[i1 * 16 + cl];
            u16x8 v2 = xb8[i2 * 16 + cl];
            u16x8 v3 = xb8[i3 * 16 + cl];
            acc += w0 * bvec2f(v0);
            acc += w1 * bvec2f(v1);
            acc += w2 * bvec2f(v2);
            acc += w3 * bvec2f(v3);
        }
        for (; e < s1; ++e) {
            int i0 = csr_src[e];
            float w0 = srcinv[i0];
            u16x8 v0 = xb8[i0 * 16 + cl];
            acc += w0 * bvec2f(v0);
        }

        float ds = 0.5f * inv[dir * NN + n];       // dest-side scale + ALPHA fold
        u16x8 o;
#pragma unroll
        for (int i = 0; i < 8; ++i) o[i] = f2bf(acc[i] * ds);
        *(u16x8*)&a_lds[nl][dir * 128 + cl * 8] = o;
    }
    __syncthreads();

    // ---- GEMM: this wave's 16x16 output tile, cols [wave*16, wave*16+16) ----
    f32x4 acc = {};
#pragma unroll
    for (int s = 0; s < 8; ++s) {
        short8 afrag = *(const short8*)&a_lds[fr][s * 32 + kg];
        acc = __builtin_amdgcn_mfma_f32_16x16x32_bf16(afrag, bfrag[s], acc, 0, 0, 0);
    }

    const int orow0 = blockIdx.x * 16 + (lane >> 4) * 4;
#pragma unroll
    for (int i = 0; i < 4; ++i) {
        out[(orow0 + i) * 128 + col] = acc[i] + b;
    }
}

extern "C" void kernel_launch(void* const* d_in, const int* in_sizes, int n_in,
                              void* d_out, int out_size, void* d_ws, size_t ws_size,
                              hipStream_t stream) {
    const float* x   = (const float*)d_in[0];
    const int* ei    = (const int*)d_in[1];
    const float* Wsd = (const float*)d_in[2];
    const float* bsd = (const float*)d_in[3];
    const float* Wds = (const float*)d_in[4];
    const float* bds = (const float*)d_in[5];

    char* ws = (char*)d_ws;
    float* inv     = (float*)(ws + OFF_INV);
    int*   offsets = (int*)(ws + OFF_OFFS);
    int*   hist    = (int*)(ws + OFF_HIST);
    int*   csr_src = (int*)(ws + OFF_CSRC);
    unsigned short* xb  = (unsigned short*)(ws + OFF_XB);
    unsigned int* pairs = (unsigned int*)(ws + OFF_PAIRS);
    unsigned short* wt  = (unsigned short*)(ws + OFF_WT);
    float* bias    = (float*)(ws + OFF_BIAS);
    int*   tot     = (int*)(ws + OFF_TOT);

    k_prep<<<GB_CVT + GB_PW + GB_HIST, 256, 0, stream>>>(
        (const float4*)x, (ushort4*)xb, Wds, Wsd, bds, bsd, wt, bias, ei, hist);
    k_colscan<<<NB, 256, 0, stream>>>(hist, tot);
    k_scatter<<<256, 256, 0, stream>>>(ei, hist, tot, pairs);
    k_bucket<<<NB, 256, 0, stream>>>(pairs, tot, csr_src, offsets, inv);
    k_gather_gemm<<<NN / 16, 512, 0, stream>>>((const u16x8*)xb, offsets, csr_src, inv,
                                               wt, bias, (float*)d_out);
}

// Round 16
// 178.080 us; speedup vs baseline: 1.0585x; 1.0585x over previous
//
#include <hip/hip_runtime.h>

#define NN 100000
#define NE 800000
#define NI 1600000      // items = 2E (both directions)
#define NB 391          // coarse buckets = ceil(2N / 512)
#define IPB 6250        // items per block in hist/scatter (256 blocks)

// grid split for fused prep kernel
#define GB_CVT 12500    // cvt_x blocks (NN*32 float4 / 256)
#define GB_PW  128      // prep_w blocks
#define GB_HIST 256     // hist blocks

// ---- workspace layout (bytes) ----
#define OFF_INV    0u           // float[2N]   [0,N)=row-keyed inv, [N,2N)=col-keyed inv
#define OFF_OFFS   800000u      // int[2N+1]
#define OFF_HIST   1601600u     // int[NB*256]
#define OFF_CSRC   2001984u     // int[2E]
#define OFF_XB     8401984u     // bf16[N*128]
#define OFF_PAIRS  34001984u    // uint[2E] packed (val<<9 | key&511)
#define OFF_WT     85201984u    // bf16[128*256] WT[c][k]: k<128 -> W_ds, else W_sd
#define OFF_BIAS   85267520u    // float[128] 0.5*(b_ds+b_sd)
#define OFF_TOT    85268032u    // int[NB]

typedef short short8 __attribute__((ext_vector_type(8)));
typedef unsigned short u16x8 __attribute__((ext_vector_type(8)));
typedef float f32x4 __attribute__((ext_vector_type(4)));
typedef float f32x8 __attribute__((ext_vector_type(8)));

__device__ __forceinline__ unsigned short f2bf(float f) {
    unsigned u = __float_as_uint(f);
    u = (u + 0x7FFFu + ((u >> 16) & 1u)) >> 16;   // RNE
    return (unsigned short)u;
}
__device__ __forceinline__ float b2f(unsigned short h) {
    return __uint_as_float(((unsigned)h) << 16);
}
__device__ __forceinline__ f32x8 bvec2f(u16x8 v) {
    f32x8 r;
#pragma unroll
    for (int i = 0; i < 8; ++i) r[i] = b2f(v[i]);
    return r;
}

// item i: i<NE  -> key=row=ei[i],      val=col=ei[NE+i]  (in-agg, keyed by row)
//         i>=NE -> key=NN+col=NN+ei[i], val=row=ei[i-NE] (out-agg, keyed by col)

// Fused: cvt_x | prep_w | hist — mutually independent work
__global__ __launch_bounds__(256) void k_prep(
    const float4* __restrict__ x4, ushort4* __restrict__ xb4,
    const float* __restrict__ Wds, const float* __restrict__ Wsd,
    const float* __restrict__ bds, const float* __restrict__ bsd,
    unsigned short* __restrict__ wt, float* __restrict__ bias,
    const int* __restrict__ ei, int* __restrict__ hist) {
    __shared__ int h[NB];
    int bid = blockIdx.x;
    if (bid < GB_CVT) {
        int i = bid * 256 + threadIdx.x;           // < NN*32 exactly
        float4 v = x4[i];
        ushort4 o;
        o.x = f2bf(v.x); o.y = f2bf(v.y); o.z = f2bf(v.z); o.w = f2bf(v.w);
        xb4[i] = o;
        return;
    }
    if (bid < GB_CVT + GB_PW) {
        int id = (bid - GB_CVT) * 256 + threadIdx.x;   // < 32768 exactly
        int c = id & 127;
        int k = id >> 7;
        float v = (k < 128) ? Wds[k * 128 + c] : Wsd[(k - 128) * 128 + c];
        wt[c * 256 + k] = f2bf(v);
        if (k == 0) bias[c] = 0.5f * (bds[c] + bsd[c]);
        return;
    }
    int hb = bid - GB_CVT - GB_PW;                  // hist block 0..255
    for (int k = threadIdx.x; k < NB; k += 256) h[k] = 0;
    __syncthreads();
    int base = hb * IPB;
    for (int t = threadIdx.x; t < IPB; t += 256) {
        int i = base + t;
        int key = (i < NE) ? ei[i] : (NN + ei[i]);
        atomicAdd(&h[key >> 9], 1);
    }
    __syncthreads();
    for (int k = threadIdx.x; k < NB; k += 256) hist[k * 256 + hb] = h[k];
}

// Per-bucket column scan: hist[k][b] -> local exclusive scan, tot[k] = total
__global__ __launch_bounds__(256) void k_colscan(int* __restrict__ hist,
                                                 int* __restrict__ tot) {
    __shared__ int sA[256], sB[256];
    int k = blockIdx.x, tid = threadIdx.x;
    int v = hist[k * 256 + tid];
    sA[tid] = v;
    __syncthreads();
    int *src = sA, *dst = sB;
    for (int st = 1; st < 256; st <<= 1) {
        dst[tid] = src[tid] + ((tid >= st) ? src[tid - st] : 0);
        __syncthreads();
        int* tp = src; src = dst; dst = tp;
    }
    hist[k * 256 + tid] = src[tid] - v;   // local exclusive scan
    if (tid == 255) tot[k] = src[255];
}

// scatter packed items; per-block cursor = in-LDS scan of tot + local hist base
__global__ __launch_bounds__(256) void k_scatter(const int* __restrict__ ei,
                                                 const int* __restrict__ hist,
                                                 const int* __restrict__ tot,
                                                 unsigned int* __restrict__ pairs) {
    __shared__ int sA[512], sB[512];
    __shared__ int cur[NB];
    const int tid = threadIdx.x;
    for (int k = tid; k < 512; k += 256) sA[k] = (k < NB) ? tot[k] : 0;
    __syncthreads();
    int *src = sA, *dst = sB;
    for (int st = 1; st < 512; st <<= 1) {
        for (int k = tid; k < 512; k += 256) dst[k] = src[k] + ((k >= st) ? src[k - st] : 0);
        __syncthreads();
        int* tp = src; src = dst; dst = tp;
    }
    for (int k = tid; k < NB; k += 256)
        cur[k] = ((k > 0) ? src[k - 1] : 0) + hist[k * 256 + blockIdx.x];
    __syncthreads();
    int base = blockIdx.x * IPB;
    for (int t = tid; t < IPB; t += 256) {
        int i = base + t;
        int e = ei[i];
        int key, val;
        if (i < NE) { key = e;      val = ei[NE + i]; }
        else        { key = NN + e; val = ei[i - NE]; }
        int pos = atomicAdd(&cur[key >> 9], 1);
        pairs[pos] = ((unsigned)val << 9) | (unsigned)(key & 511);
    }
}

// one block per bucket: bucket base from in-LDS tot scan, then count/scan/emit
__global__ __launch_bounds__(256) void k_bucket(const unsigned int* __restrict__ pairs,
                                                const int* __restrict__ tot,
                                                int* __restrict__ csr_src,
                                                int* __restrict__ offsets,
                                                float* __restrict__ inv) {
    __shared__ int sA[512], sB[512], cur[512];
    const int h = blockIdx.x, tid = threadIdx.x;
    // phase 0: scan tot -> bucket bounds
    for (int k = tid; k < 512; k += 256) sA[k] = (k < NB) ? tot[k] : 0;
    __syncthreads();
    int *src = sA, *dst = sB;
    for (int st = 1; st < 512; st <<= 1) {
        for (int k = tid; k < 512; k += 256) dst[k] = src[k] + ((k >= st) ? src[k - st] : 0);
        __syncthreads();
        int* tp = src; src = dst; dst = tp;
    }
    const int s0 = (h > 0) ? src[h - 1] : 0;
    const int s1 = src[h];
    __syncthreads();
    // phase 1: local key count
    for (int k = tid; k < 512; k += 256) sA[k] = 0;
    __syncthreads();
    for (int i = s0 + tid; i < s1; i += 256) {
        atomicAdd(&sA[pairs[i] & 511], 1);
    }
    __syncthreads();
    src = sA; dst = sB;
    for (int st = 1; st < 512; st <<= 1) {
        for (int k = tid; k < 512; k += 256) dst[k] = src[k] + ((k >= st) ? src[k - st] : 0);
        __syncthreads();
        int* tp = src; src = dst; dst = tp;
    }
    for (int k = tid; k < 512; k += 256) {
        int incl = src[k];
        int excl = (k > 0) ? src[k - 1] : 0;
        cur[k] = s0 + excl;
        int gkey = h * 512 + k;
        if (gkey <= 2 * NN) offsets[gkey] = s0 + excl;
        if (gkey < 2 * NN) {
            int cnt = incl - excl;
            inv[gkey] = (cnt > 0) ? rsqrtf((float)cnt) : 0.0f;
        }
    }
    __syncthreads();
    for (int i = s0 + tid; i < s1; i += 256) {
        unsigned int p = pairs[i];
        int pos = atomicAdd(&cur[p & 511], 1);
        csr_src[pos] = (int)(p >> 9);
    }
}

// Fused gather + GEMM — proven optimum (117 us, 81% occ, VGPR 32).
// Block = 512 threads (8 waves), 16 nodes, 32 segments, grid 6250.
// Gather: 32 groups of 16 lanes, 1 segment each, 4-deep unrolled row loads.
// LDS [16][264]: 528B rows, u16x8 ops 16B-aligned. 8.4 KB/block.
// GEMM: wave w computes col-tile w (16 cols x 16 rows), K=256.
// NOTE: do NOT hold wt fragments across the gather (R15: +16 VGPR ->
// occupancy 81->43%); do NOT widen per-group work (R9/R10); do NOT
// drop the barrier (R12); do NOT degree-balance (R13).
__global__ __launch_bounds__(512) void k_gather_gemm(
    const u16x8* __restrict__ xb8, const int* __restrict__ offsets,
    const int* __restrict__ csr_src, const float* __restrict__ inv,
    const unsigned short* __restrict__ wt, const float* __restrict__ bias,
    float* __restrict__ out) {
    __shared__ unsigned short a_lds[16][264];

    const int wave = threadIdx.x >> 6;
    const int lane = threadIdx.x & 63;
    const int grp = lane >> 4;                 // 0..3
    const int cl = lane & 15;
    const int nl = wave * 2 + (grp >> 1);      // local node 0..15
    const int n = blockIdx.x * 16 + nl;        // 6250*16 == NN exactly
    const int dir = grp & 1;                   // 0 = in-agg, 1 = out-agg

    {
        int key = dir * NN + n;
        int s0 = offsets[key], s1 = offsets[key + 1];
        const float* __restrict__ srcinv = inv + (dir ^ 1) * NN;

        f32x8 acc = {0.f, 0.f, 0.f, 0.f, 0.f, 0.f, 0.f, 0.f};
        int e = s0;
        for (; e + 4 <= s1; e += 4) {
            int i0 = csr_src[e];
            int i1 = csr_src[e + 1];
            int i2 = csr_src[e + 2];
            int i3 = csr_src[e + 3];
            float w0 = srcinv[i0], w1 = srcinv[i1], w2 = srcinv[i2], w3 = srcinv[i3];
            u16x8 v0 = xb8[i0 * 16 + cl];
            u16x8 v1 = xb8[i1 * 16 + cl];
            u16x8 v2 = xb8[i2 * 16 + cl];
            u16x8 v3 = xb8[i3 * 16 + cl];
            acc += w0 * bvec2f(v0);
            acc += w1 * bvec2f(v1);
            acc += w2 * bvec2f(v2);
            acc += w3 * bvec2f(v3);
        }
        for (; e < s1; ++e) {
            int i0 = csr_src[e];
            float w0 = srcinv[i0];
            u16x8 v0 = xb8[i0 * 16 + cl];
            acc += w0 * bvec2f(v0);
        }

        float ds = 0.5f * inv[dir * NN + n];       // dest-side scale + ALPHA fold
        u16x8 o;
#pragma unroll
        for (int i = 0; i < 8; ++i) o[i] = f2bf(acc[i] * ds);
        *(u16x8*)&a_lds[nl][dir * 128 + cl * 8] = o;
    }
    __syncthreads();

    // GEMM: this wave's 16x16 output tile, cols [wave*16, wave*16+16)
    const int fr = lane & 15;
    const int kg = (lane >> 4) * 8;
    const int col = wave * 16 + fr;

    f32x4 acc = {};
#pragma unroll
    for (int s = 0; s < 8; ++s) {
        short8 afrag = *(const short8*)&a_lds[fr][s * 32 + kg];
        short8 bfrag = *(const short8*)(wt + col * 256 + s * 32 + kg);
        acc = __builtin_amdgcn_mfma_f32_16x16x32_bf16(afrag, bfrag, acc, 0, 0, 0);
    }

    const float b = bias[col];
    const int orow0 = blockIdx.x * 16 + (lane >> 4) * 4;
#pragma unroll
    for (int i = 0; i < 4; ++i) {
        out[(orow0 + i) * 128 + col] = acc[i] + b;
    }
}

extern "C" void kernel_launch(void* const* d_in, const int* in_sizes, int n_in,
                              void* d_out, int out_size, void* d_ws, size_t ws_size,
                              hipStream_t stream) {
    const float* x   = (const float*)d_in[0];
    const int* ei    = (const int*)d_in[1];
    const float* Wsd = (const float*)d_in[2];
    const float* bsd = (const float*)d_in[3];
    const float* Wds = (const float*)d_in[4];
    const float* bds = (const float*)d_in[5];

    char* ws = (char*)d_ws;
    float* inv     = (float*)(ws + OFF_INV);
    int*   offsets = (int*)(ws + OFF_OFFS);
    int*   hist    = (int*)(ws + OFF_HIST);
    int*   csr_src = (int*)(ws + OFF_CSRC);
    unsigned short* xb  = (unsigned short*)(ws + OFF_XB);
    unsigned int* pairs = (unsigned int*)(ws + OFF_PAIRS);
    unsigned short* wt  = (unsigned short*)(ws + OFF_WT);
    float* bias    = (float*)(ws + OFF_BIAS);
    int*   tot     = (int*)(ws + OFF_TOT);

    k_prep<<<GB_CVT + GB_PW + GB_HIST, 256, 0, stream>>>(
        (const float4*)x, (ushort4*)xb, Wds, Wsd, bds, bsd, wt, bias, ei, hist);
    k_colscan<<<NB, 256, 0, stream>>>(hist, tot);
    k_scatter<<<256, 256, 0, stream>>>(ei, hist, tot, pairs);
    k_bucket<<<NB, 256, 0, stream>>>(pairs, tot, csr_src, offsets, inv);
    k_gather_gemm<<<NN / 16, 512, 0, stream>>>((const u16x8*)xb, offsets, csr_src, inv,
                                               wt, bias, (float*)d_out);
}